// Round 12
// baseline (69.544 us; speedup 1.0000x reference)
//
#include <hip/hip_runtime.h>
#include <hip/hip_bf16.h>

typedef unsigned long long u64;
typedef unsigned int u32;

#define NB 64
#define NP 2048
#define NT 256
#define TK 8          // sorted top-K kept per row
#define RB 8          // rows resolved per greedy batch (RB*TK = 64 lanes)
#define TT 4          // targets per cost block
#define PB 64         // preds per cost block (one wave)
#define EPSF 1e-7f

__device__ inline float iou1(const float4 pb, const float ap,
                             const float4 tb, const float at_eps) {
    float ix1 = fmaxf(pb.x, tb.x);
    float iy1 = fmaxf(pb.y, tb.y);
    float ix2 = fminf(pb.z, tb.z);
    float iy2 = fminf(pb.w, tb.w);
    float dx = fmaxf(ix2 - ix1, 0.f);
    float dy = fmaxf(iy2 - iy1, 0.f);
    float inter = dx * dy;
    float uni = (ap + at_eps) - inter;
    return inter * __builtin_amdgcn_rcpf(uni);
}

// K1: cost[t][p] = 1 - mean_b iou. Grid (32,64), single-wave blocks.
// ALL per-(b,tt) data hoisted to registers in 5 batched ds_read_b128 per
// batch-elem; the 16 IoUs per group are pure-VALU on registers.
__global__ __launch_bounds__(64) void cost_kernel(const float4* __restrict__ pred,
                                                  const float* __restrict__ tgt,
                                                  float* __restrict__ cost) {
    __shared__ float4 sT[NB * TT];                 // [b][tt] coords
    __shared__ __align__(16) float sAf[NB * TT];   // [b][tt] area+eps
    const int lane = threadIdx.x;
    const int p = blockIdx.x * PB + lane;
    const int t0 = blockIdx.y * TT;

#pragma unroll
    for (int i = lane; i < NB * TT; i += 64) {
        int b = i >> 2, tt = i & 3;
        float4 tb = *(const float4*)&tgt[(b * NT + t0 + tt) * 4];
        sT[i] = tb;
        sAf[i] = (tb.z - tb.x) * (tb.w - tb.y) + EPSF;
    }
    __syncthreads();

    float acc[TT] = {0.f, 0.f, 0.f, 0.f};

    for (int b = 0; b < NB; b += 4) {
        float4 pb[4];
#pragma unroll
        for (int u = 0; u < 4; ++u) pb[u] = pred[(b + u) * NP + p];
#pragma unroll
        for (int u = 0; u < 4; ++u) {
            // batched LDS reads (independent -> one lgkmcnt drain)
            const float4 T0 = sT[(b + u) * 4 + 0];
            const float4 T1 = sT[(b + u) * 4 + 1];
            const float4 T2 = sT[(b + u) * 4 + 2];
            const float4 T3 = sT[(b + u) * 4 + 3];
            const float4 A4 = *(const float4*)&sAf[(b + u) * 4];
            const float ap = (pb[u].z - pb[u].x) * (pb[u].w - pb[u].y);
            acc[0] += iou1(pb[u], ap, T0, A4.x);
            acc[1] += iou1(pb[u], ap, T1, A4.y);
            acc[2] += iou1(pb[u], ap, T2, A4.z);
            acc[3] += iou1(pb[u], ap, T3, A4.w);
        }
    }
#pragma unroll
    for (int tt = 0; tt < TT; ++tt)
        cost[(size_t)(t0 + tt) * NP + p] = 1.f - acc[tt] * (1.f / NB);
}

__device__ inline u64 wave_min_u64(u64 k) {
#pragma unroll
    for (int off = 1; off < 64; off <<= 1) {
        u32 lo = (u32)__shfl_xor((int)(u32)k, off);
        u32 hi = (u32)__shfl_xor((int)(u32)(k >> 32), off);
        u64 o = ((u64)hi << 32) | lo;
        if (o < k) k = o;
    }
    return k;  // uniform across lanes
}

// cold path: exact masked argmin over the full cost row (first-occurrence)
__device__ void fallback_pick(const float* __restrict__ row, u32 m, int lane,
                              u32* pickIdx, float* pickVal) {
    u64 best = ~0ull;
#pragma unroll 1
    for (int k = 0; k < 8; ++k) {
        float4 q = *(const float4*)(row + k * 256 + 4 * lane);
        float vv[4] = {q.x, q.y, q.z, q.w};
#pragma unroll
        for (int e = 0; e < 4; ++e) {
            u32 gidx = (u32)(k * 256 + 4 * lane + e);
            int w = __builtin_amdgcn_ds_bpermute((int)((gidx >> 5) << 2), (int)m);
            bool taken = (((u32)w >> (gidx & 31)) & 1u) != 0u;
            u32 hb = taken ? 0xFFFFFFFFu : __float_as_uint(vv[e]);
            u64 key = ((u64)hb << 32) | gidx;
            if (key < best) best = key;
        }
    }
    best = wave_min_u64(best);
    *pickIdx = (u32)best & (NP - 1);
    *pickVal = __uint_as_float((u32)(best >> 32));
}

// greedy: serial, one wave, toplist register-resident (validated 5 rounds)
__device__ inline void phase3_greedy(const u64* __restrict__ toplist,
                                     const float* __restrict__ cost,
                                     float* __restrict__ out, int lane) {
    u32 idxr[32], vbr[32];
#pragma unroll
    for (int k = 0; k < 32; ++k) {
        u64 v = toplist[64 * k + lane];
        idxr[k] = (u32)v & (NP - 1);
        vbr[k] = (u32)(v >> 32);
    }

    u32 m = 0;
    float sum = 0.f;
    u64 A = ~0ull;

#pragma unroll
    for (int k = 0; k < 32; ++k) {
        const u32 idx = idxr[k];
        const u32 vb = vbr[k];
        int wn = 0;
        if (k < 31)
            wn = __builtin_amdgcn_ds_bpermute((int)((idxr[k + 1] >> 5) << 2), (int)m);

        u32 pk[RB];
#pragma unroll
        for (int gg = 0; gg < RB; ++gg) {
            u64 bal = A & (0xFFull << (8 * gg));
            u32 pickIdx; float pickVal;
            if (bal != 0) {                          // uniform branch
                int f = (int)__ffsll(bal) - 1;       // lowest lane = lowest rank
                pickIdx = (u32)__builtin_amdgcn_readlane((int)idx, f);
                pickVal = __uint_as_float((u32)__builtin_amdgcn_readlane((int)vb, f));
            } else {
                fallback_pick(cost + (size_t)(k * RB + gg) * NP, m, lane,
                              &pickIdx, &pickVal);
            }
            pk[gg] = pickIdx;
            sum += pickVal;
            if ((pickIdx >> 5) == (u32)lane) m |= (1u << (pickIdx & 31));
            A &= ~__ballot(idx == pickIdx);          // clear pick + in-batch dups
        }

        if (k < 31) {
            const u32 idn = idxr[k + 1];
            u64 An = __ballot((((u32)wn >> (idn & 31)) & 1u) == 0u);
#pragma unroll
            for (int gg = 0; gg < RB; ++gg)
                An &= ~__ballot(idn == pk[gg]);
            A = An;
        }
    }
    if (lane == 0) out[0] = sum * (1.f / NT);
}

// K2: per-row top-8 (4-wave quarters + wave-0 merge), then last-arriver
// promotion: the 256th block to finish runs greedy on its wave 0 — removes
// one graph node. Work assignment nondeterministic, output deterministic.
__global__ __launch_bounds__(256) void topk_kernel(const float* __restrict__ cost,
                                                   u64* __restrict__ toplist,
                                                   u32* __restrict__ done,
                                                   float* __restrict__ out) {
    __shared__ u64 sK[32];
    __shared__ int sLast;
    const int tid = threadIdx.x;
    const int wv = tid >> 6, lane = tid & 63;
    const int t = blockIdx.x;
    const float* row = cost + (size_t)t * NP;

    float v[8];
#pragma unroll
    for (int c = 0; c < 2; ++c) {
        float4 q = *(const float4*)(row + wv * 512 + c * 256 + 4 * lane);
        v[4 * c + 0] = q.x; v[4 * c + 1] = q.y;
        v[4 * c + 2] = q.z; v[4 * c + 3] = q.w;
    }
    u32 used = 0;
    for (int e = 0; e < TK; ++e) {
        u64 best = ~0ull;
        u32 bs = 0;
#pragma unroll
        for (int s = 0; s < 8; ++s) {
            u32 hb = ((used >> s) & 1u) ? 0xFFFFFFFFu : __float_as_uint(v[s]);
            u32 gidx = (u32)(wv * 512 + (s >> 2) * 256 + 4 * lane + (s & 3));
            u64 key = ((u64)hb << 32) | gidx;
            if (key < best) { best = key; bs = (u32)s; }
        }
        u64 g = wave_min_u64(best);
        if (best == g) used |= (1u << bs);   // unique winner (idx in key)
        if (lane == 0) sK[wv * TK + e] = g;
    }
    __syncthreads();
    if (wv == 0) {
        u64 k = (lane < 32) ? sK[lane] : ~0ull;
        for (int e = 0; e < TK; ++e) {
            u64 g = wave_min_u64(k);
            if (k == g) k = ~0ull;           // clear unique winner
            if (lane == 0) toplist[t * TK + e] = g;
        }
    }
    __syncthreads();
    if (tid == 0) {
        __threadfence();                     // release this row's toplist
        sLast = (atomicAdd(done, 1u) == NT - 1);
    }
    __syncthreads();
    if (sLast) {                             // block-uniform
        __threadfence();                     // acquire all rows' toplist/cost
        if (tid < 64) phase3_greedy(toplist, cost, out, tid);
    }
}

extern "C" void kernel_launch(void* const* d_in, const int* in_sizes, int n_in,
                              void* d_out, int out_size, void* d_ws, size_t ws_size,
                              hipStream_t stream) {
    const float4* pred = (const float4*)d_in[0];
    const float* tgt = (const float*)d_in[1];
    char* ws = (char*)d_ws;
    float* cost  = (float*)ws;                                       // 2 MB
    u64* toplist = (u64*)(ws + (size_t)NT * NP * 4);                 // 16 KB
    u32* done    = (u32*)(ws + (size_t)NT * NP * 4 + NT * TK * 8);   // 4 B

    hipMemsetAsync(done, 0, sizeof(u32), stream);
    cost_kernel<<<dim3(NP / PB, NT / TT), PB, 0, stream>>>(pred, tgt, cost);
    topk_kernel<<<NT, 256, 0, stream>>>(cost, toplist, done, (float*)d_out);
}

// Round 13
// 53.370 us; speedup vs baseline: 1.3031x; 1.3031x over previous
//
#include <hip/hip_runtime.h>
#include <hip/hip_bf16.h>

typedef unsigned long long u64;
typedef unsigned int u32;

#define NB 64
#define NP 2048
#define NT 256
#define TK 8          // sorted top-K kept per row
#define RB 8          // rows resolved per greedy batch (RB*TK = 64 lanes)
#define TT 4          // targets per cost block
#define PB 64         // preds per cost block
#define EPSF 1e-7f

__device__ inline float iou1(const float4 pb, const float ap,
                             const float4 tb, const float at_eps) {
    float ix1 = fmaxf(pb.x, tb.x);
    float iy1 = fmaxf(pb.y, tb.y);
    float ix2 = fminf(pb.z, tb.z);
    float iy2 = fminf(pb.w, tb.w);
    float dx = fmaxf(ix2 - ix1, 0.f);
    float dy = fmaxf(iy2 - iy1, 0.f);
    float inter = dx * dy;
    float uni = (ap + at_eps) - inter;
    return inter * __builtin_amdgcn_rcpf(uni);
}

// K1: cost[t][p] = 1 - mean_b iou. Grid (32,64) x 256 thr = 8192 waves
// (8/SIMD for latency hiding). Wave w covers batches [16w,16w+16); pure-VALU
// register inner loop (targets hoisted from LDS in batched ds_read_b128);
// cross-wave reduce in LDS at the end.
__global__ __launch_bounds__(256) void cost_kernel(const float4* __restrict__ pred,
                                                   const float* __restrict__ tgt,
                                                   float* __restrict__ cost) {
    __shared__ float4 sT[NB * TT];                 // [b][tt] coords  (4 KB)
    __shared__ __align__(16) float sAf[NB * TT];   // [b][tt] area+eps (1 KB)
    __shared__ float sRed[4][TT][PB];              // per-wave partials (4 KB)
    const int tid = threadIdx.x;
    const int wv = tid >> 6, lane = tid & 63;
    const int p = blockIdx.x * PB + lane;
    const int t0 = blockIdx.y * TT;

    {   // cooperative staging: 256 threads, one (b,tt) each
        int b = tid >> 2, tt = tid & 3;
        float4 tb = *(const float4*)&tgt[(b * NT + t0 + tt) * 4];
        sT[tid] = tb;
        sAf[tid] = (tb.z - tb.x) * (tb.w - tb.y) + EPSF;
    }
    __syncthreads();

    float acc[TT] = {0.f, 0.f, 0.f, 0.f};

    const int b0 = wv * (NB / 4);
    for (int bo = 0; bo < NB / 4; bo += 4) {
        float4 pb[4];
#pragma unroll
        for (int u = 0; u < 4; ++u) pb[u] = pred[(b0 + bo + u) * NP + p];
#pragma unroll
        for (int u = 0; u < 4; ++u) {
            const int b = b0 + bo + u;
            const float4 T0 = sT[b * 4 + 0];
            const float4 T1 = sT[b * 4 + 1];
            const float4 T2 = sT[b * 4 + 2];
            const float4 T3 = sT[b * 4 + 3];
            const float4 A4 = *(const float4*)&sAf[b * 4];
            const float ap = (pb[u].z - pb[u].x) * (pb[u].w - pb[u].y);
            acc[0] += iou1(pb[u], ap, T0, A4.x);
            acc[1] += iou1(pb[u], ap, T1, A4.y);
            acc[2] += iou1(pb[u], ap, T2, A4.z);
            acc[3] += iou1(pb[u], ap, T3, A4.w);
        }
    }
#pragma unroll
    for (int tt = 0; tt < TT; ++tt) sRed[wv][tt][lane] = acc[tt];
    __syncthreads();

    {   // 256 threads: one (tt,lane) each -> coalesced store
        const int tt = tid >> 6, l = tid & 63;
        float s = sRed[0][tt][l] + sRed[1][tt][l] + sRed[2][tt][l] + sRed[3][tt][l];
        cost[(size_t)(t0 + tt) * NP + blockIdx.x * PB + l] = 1.f - s * (1.f / NB);
    }
}

__device__ inline u64 wave_min_u64(u64 k) {
#pragma unroll
    for (int off = 1; off < 64; off <<= 1) {
        u32 lo = (u32)__shfl_xor((int)(u32)k, off);
        u32 hi = (u32)__shfl_xor((int)(u32)(k >> 32), off);
        u64 o = ((u64)hi << 32) | lo;
        if (o < k) k = o;
    }
    return k;  // uniform across lanes
}

// K2: 4 waves/row. Each wave extracts sorted top-8 of its 512-element quarter
// on packed (valbits<<32 | idx) keys; wave 0 merges the 32 candidates.
__global__ __launch_bounds__(256) void topk_kernel(const float* __restrict__ cost,
                                                   u64* __restrict__ toplist) {
    __shared__ u64 sK[32];
    const int tid = threadIdx.x;
    const int wv = tid >> 6, lane = tid & 63;
    const int t = blockIdx.x;
    const float* row = cost + (size_t)t * NP;

    float v[8];
#pragma unroll
    for (int c = 0; c < 2; ++c) {
        float4 q = *(const float4*)(row + wv * 512 + c * 256 + 4 * lane);
        v[4 * c + 0] = q.x; v[4 * c + 1] = q.y;
        v[4 * c + 2] = q.z; v[4 * c + 3] = q.w;
    }
    u32 used = 0;
    for (int e = 0; e < TK; ++e) {
        u64 best = ~0ull;
        u32 bs = 0;
#pragma unroll
        for (int s = 0; s < 8; ++s) {
            u32 hb = ((used >> s) & 1u) ? 0xFFFFFFFFu : __float_as_uint(v[s]);
            u32 gidx = (u32)(wv * 512 + (s >> 2) * 256 + 4 * lane + (s & 3));
            u64 key = ((u64)hb << 32) | gidx;
            if (key < best) { best = key; bs = (u32)s; }
        }
        u64 g = wave_min_u64(best);
        if (best == g) used |= (1u << bs);   // unique winner (idx in key)
        if (lane == 0) sK[wv * TK + e] = g;
    }
    __syncthreads();
    if (wv == 0) {
        u64 k = (lane < 32) ? sK[lane] : ~0ull;
        for (int e = 0; e < TK; ++e) {
            u64 g = wave_min_u64(k);
            if (k == g) k = ~0ull;           // clear unique winner
            if (lane == 0) toplist[t * TK + e] = g;
        }
    }
}

// cold path: exact masked argmin over the full cost row (first-occurrence)
__device__ void fallback_pick(const float* __restrict__ row, u32 m, int lane,
                              u32* pickIdx, float* pickVal) {
    u64 best = ~0ull;
#pragma unroll 1
    for (int k = 0; k < 8; ++k) {
        float4 q = *(const float4*)(row + k * 256 + 4 * lane);
        float vv[4] = {q.x, q.y, q.z, q.w};
#pragma unroll
        for (int e = 0; e < 4; ++e) {
            u32 gidx = (u32)(k * 256 + 4 * lane + e);
            int w = __builtin_amdgcn_ds_bpermute((int)((gidx >> 5) << 2), (int)m);
            bool taken = (((u32)w >> (gidx & 31)) & 1u) != 0u;
            u32 hb = taken ? 0xFFFFFFFFu : __float_as_uint(vv[e]);
            u64 key = ((u64)hb << 32) | gidx;
            if (key < best) best = key;
        }
    }
    best = wave_min_u64(best);
    *pickIdx = (u32)best & (NP - 1);
    *pickVal = __uint_as_float((u32)(best >> 32));
}

// K3: serial greedy, one wave, toplist fully register-resident (validated).
__global__ __launch_bounds__(64) void greedy_kernel(const u64* __restrict__ toplist,
                                                    const float* __restrict__ cost,
                                                    float* __restrict__ out) {
    const int lane = threadIdx.x;
    u32 idxr[32], vbr[32];
#pragma unroll
    for (int k = 0; k < 32; ++k) {
        u64 v = toplist[64 * k + lane];
        idxr[k] = (u32)v & (NP - 1);
        vbr[k] = (u32)(v >> 32);
    }

    u32 m = 0;
    float sum = 0.f;
    u64 A = ~0ull;

#pragma unroll
    for (int k = 0; k < 32; ++k) {
        const u32 idx = idxr[k];
        const u32 vb = vbr[k];
        int wn = 0;
        if (k < 31)
            wn = __builtin_amdgcn_ds_bpermute((int)((idxr[k + 1] >> 5) << 2), (int)m);

        u32 pk[RB];
#pragma unroll
        for (int gg = 0; gg < RB; ++gg) {
            u64 bal = A & (0xFFull << (8 * gg));
            u32 pickIdx; float pickVal;
            if (bal != 0) {                          // uniform branch
                int f = (int)__ffsll(bal) - 1;       // lowest lane = lowest rank
                pickIdx = (u32)__builtin_amdgcn_readlane((int)idx, f);
                pickVal = __uint_as_float((u32)__builtin_amdgcn_readlane((int)vb, f));
            } else {
                fallback_pick(cost + (size_t)(k * RB + gg) * NP, m, lane,
                              &pickIdx, &pickVal);
            }
            pk[gg] = pickIdx;
            sum += pickVal;
            if ((pickIdx >> 5) == (u32)lane) m |= (1u << (pickIdx & 31));
            A &= ~__ballot(idx == pickIdx);          // clear pick + in-batch dups
        }

        if (k < 31) {
            const u32 idn = idxr[k + 1];
            u64 An = __ballot((((u32)wn >> (idn & 31)) & 1u) == 0u);
#pragma unroll
            for (int gg = 0; gg < RB; ++gg)
                An &= ~__ballot(idn == pk[gg]);
            A = An;
        }
    }
    if (lane == 0) out[0] = sum * (1.f / NT);
}

extern "C" void kernel_launch(void* const* d_in, const int* in_sizes, int n_in,
                              void* d_out, int out_size, void* d_ws, size_t ws_size,
                              hipStream_t stream) {
    const float4* pred = (const float4*)d_in[0];
    const float* tgt = (const float*)d_in[1];
    char* ws = (char*)d_ws;
    float* cost  = (float*)ws;                           // 2 MB
    u64* toplist = (u64*)(ws + (size_t)NT * NP * 4);     // 16 KB

    cost_kernel<<<dim3(NP / PB, NT / TT), 256, 0, stream>>>(pred, tgt, cost);
    topk_kernel<<<NT, 256, 0, stream>>>(cost, toplist);
    greedy_kernel<<<1, 64, 0, stream>>>(toplist, cost, (float*)d_out);
}

// Round 14
// 52.405 us; speedup vs baseline: 1.3271x; 1.0184x over previous
//
#include <hip/hip_runtime.h>
#include <hip/hip_bf16.h>

typedef unsigned long long u64;
typedef unsigned int u32;

#define NB 64
#define NP 2048
#define NT 256
#define TK 8          // sorted top-K kept per row
#define RB 8          // rows resolved per greedy batch (RB*TK = 64 lanes)
#define TT 8          // targets per cost block
#define PB 64         // preds per cost block
#define EPSF 1e-7f

__device__ inline float iou1(const float4 pb, const float ap,
                             const float4 tb, const float at_eps) {
    float ix1 = fmaxf(pb.x, tb.x);
    float iy1 = fmaxf(pb.y, tb.y);
    float ix2 = fminf(pb.z, tb.z);
    float iy2 = fminf(pb.w, tb.w);
    float dx = fmaxf(ix2 - ix1, 0.f);
    float dy = fmaxf(iy2 - iy1, 0.f);
    float inter = dx * dy;
    float uni = (ap + at_eps) - inter;
    return inter * __builtin_amdgcn_rcpf(uni);
}

// K1: cost[t][p] = 1 - mean_b iou. Grid (32,32) x 512 thr = 8 waves/block,
// 4 blocks/CU -> 32 waves/CU (same TLP as R13) with 2x arithmetic intensity:
// each pred float4 feeds 8 IoUs; LDS reads per IoU halved vs R13.
// Wave w covers batches [8w, 8w+8); cross-wave 8-way reduce in LDS.
__global__ __launch_bounds__(512) void cost_kernel(const float4* __restrict__ pred,
                                                   const float* __restrict__ tgt,
                                                   float* __restrict__ cost) {
    __shared__ float4 sT[NB * TT];                 // [b][tt] coords   (8 KB)
    __shared__ __align__(16) float sAf[NB * TT];   // [b][tt] area+eps (2 KB)
    __shared__ float sRed[8][TT][PB];              // per-wave partials (16 KB)
    const int tid = threadIdx.x;
    const int wv = tid >> 6, lane = tid & 63;
    const int p = blockIdx.x * PB + lane;
    const int t0 = blockIdx.y * TT;

    {   // cooperative staging: 512 threads, one (b,tt) each
        int b = tid >> 3, tt = tid & 7;
        float4 tb = *(const float4*)&tgt[(b * NT + t0 + tt) * 4];
        sT[tid] = tb;
        sAf[tid] = (tb.z - tb.x) * (tb.w - tb.y) + EPSF;
    }
    __syncthreads();

    float acc[TT] = {0.f, 0.f, 0.f, 0.f, 0.f, 0.f, 0.f, 0.f};

    const int b0 = wv * (NB / 8);
    {
        float4 pb[8];
#pragma unroll
        for (int u = 0; u < 8; ++u) pb[u] = pred[(b0 + u) * NP + p];
#pragma unroll
        for (int u = 0; u < 8; ++u) {
            const int b = b0 + u;
            const float ap = (pb[u].z - pb[u].x) * (pb[u].w - pb[u].y);
#pragma unroll
            for (int tt = 0; tt < TT; ++tt) {
                // broadcast LDS reads, consumed immediately (low VGPR)
                acc[tt] += iou1(pb[u], ap, sT[b * TT + tt], sAf[b * TT + tt]);
            }
        }
    }
#pragma unroll
    for (int tt = 0; tt < TT; ++tt) sRed[wv][tt][lane] = acc[tt];
    __syncthreads();

    {   // 512 threads: one (tt,lane) each -> coalesced store
        const int tt = tid >> 6, l = tid & 63;
        float s = 0.f;
#pragma unroll
        for (int w = 0; w < 8; ++w) s += sRed[w][tt][l];
        cost[(size_t)(t0 + tt) * NP + blockIdx.x * PB + l] = 1.f - s * (1.f / NB);
    }
}

__device__ inline u64 wave_min_u64(u64 k) {
#pragma unroll
    for (int off = 1; off < 64; off <<= 1) {
        u32 lo = (u32)__shfl_xor((int)(u32)k, off);
        u32 hi = (u32)__shfl_xor((int)(u32)(k >> 32), off);
        u64 o = ((u64)hi << 32) | lo;
        if (o < k) k = o;
    }
    return k;  // uniform across lanes
}

// K2: 4 waves/row. Each wave extracts sorted top-8 of its 512-element quarter
// on packed (valbits<<32 | idx) keys; wave 0 merges the 32 candidates.
__global__ __launch_bounds__(256) void topk_kernel(const float* __restrict__ cost,
                                                   u64* __restrict__ toplist) {
    __shared__ u64 sK[32];
    const int tid = threadIdx.x;
    const int wv = tid >> 6, lane = tid & 63;
    const int t = blockIdx.x;
    const float* row = cost + (size_t)t * NP;

    float v[8];
#pragma unroll
    for (int c = 0; c < 2; ++c) {
        float4 q = *(const float4*)(row + wv * 512 + c * 256 + 4 * lane);
        v[4 * c + 0] = q.x; v[4 * c + 1] = q.y;
        v[4 * c + 2] = q.z; v[4 * c + 3] = q.w;
    }
    u32 used = 0;
    for (int e = 0; e < TK; ++e) {
        u64 best = ~0ull;
        u32 bs = 0;
#pragma unroll
        for (int s = 0; s < 8; ++s) {
            u32 hb = ((used >> s) & 1u) ? 0xFFFFFFFFu : __float_as_uint(v[s]);
            u32 gidx = (u32)(wv * 512 + (s >> 2) * 256 + 4 * lane + (s & 3));
            u64 key = ((u64)hb << 32) | gidx;
            if (key < best) { best = key; bs = (u32)s; }
        }
        u64 g = wave_min_u64(best);
        if (best == g) used |= (1u << bs);   // unique winner (idx in key)
        if (lane == 0) sK[wv * TK + e] = g;
    }
    __syncthreads();
    if (wv == 0) {
        u64 k = (lane < 32) ? sK[lane] : ~0ull;
        for (int e = 0; e < TK; ++e) {
            u64 g = wave_min_u64(k);
            if (k == g) k = ~0ull;           // clear unique winner
            if (lane == 0) toplist[t * TK + e] = g;
        }
    }
}

// cold path: exact masked argmin over the full cost row (first-occurrence)
__device__ void fallback_pick(const float* __restrict__ row, u32 m, int lane,
                              u32* pickIdx, float* pickVal) {
    u64 best = ~0ull;
#pragma unroll 1
    for (int k = 0; k < 8; ++k) {
        float4 q = *(const float4*)(row + k * 256 + 4 * lane);
        float vv[4] = {q.x, q.y, q.z, q.w};
#pragma unroll
        for (int e = 0; e < 4; ++e) {
            u32 gidx = (u32)(k * 256 + 4 * lane + e);
            int w = __builtin_amdgcn_ds_bpermute((int)((gidx >> 5) << 2), (int)m);
            bool taken = (((u32)w >> (gidx & 31)) & 1u) != 0u;
            u32 hb = taken ? 0xFFFFFFFFu : __float_as_uint(vv[e]);
            u64 key = ((u64)hb << 32) | gidx;
            if (key < best) best = key;
        }
    }
    best = wave_min_u64(best);
    *pickIdx = (u32)best & (NP - 1);
    *pickVal = __uint_as_float((u32)(best >> 32));
}

// K3: serial greedy, one wave, toplist fully register-resident (validated).
__global__ __launch_bounds__(64) void greedy_kernel(const u64* __restrict__ toplist,
                                                    const float* __restrict__ cost,
                                                    float* __restrict__ out) {
    const int lane = threadIdx.x;
    u32 idxr[32], vbr[32];
#pragma unroll
    for (int k = 0; k < 32; ++k) {
        u64 v = toplist[64 * k + lane];
        idxr[k] = (u32)v & (NP - 1);
        vbr[k] = (u32)(v >> 32);
    }

    u32 m = 0;
    float sum = 0.f;
    u64 A = ~0ull;

#pragma unroll
    for (int k = 0; k < 32; ++k) {
        const u32 idx = idxr[k];
        const u32 vb = vbr[k];
        int wn = 0;
        if (k < 31)
            wn = __builtin_amdgcn_ds_bpermute((int)((idxr[k + 1] >> 5) << 2), (int)m);

        u32 pk[RB];
#pragma unroll
        for (int gg = 0; gg < RB; ++gg) {
            u64 bal = A & (0xFFull << (8 * gg));
            u32 pickIdx; float pickVal;
            if (bal != 0) {                          // uniform branch
                int f = (int)__ffsll(bal) - 1;       // lowest lane = lowest rank
                pickIdx = (u32)__builtin_amdgcn_readlane((int)idx, f);
                pickVal = __uint_as_float((u32)__builtin_amdgcn_readlane((int)vb, f));
            } else {
                fallback_pick(cost + (size_t)(k * RB + gg) * NP, m, lane,
                              &pickIdx, &pickVal);
            }
            pk[gg] = pickIdx;
            sum += pickVal;
            if ((pickIdx >> 5) == (u32)lane) m |= (1u << (pickIdx & 31));
            A &= ~__ballot(idx == pickIdx);          // clear pick + in-batch dups
        }

        if (k < 31) {
            const u32 idn = idxr[k + 1];
            u64 An = __ballot((((u32)wn >> (idn & 31)) & 1u) == 0u);
#pragma unroll
            for (int gg = 0; gg < RB; ++gg)
                An &= ~__ballot(idn == pk[gg]);
            A = An;
        }
    }
    if (lane == 0) out[0] = sum * (1.f / NT);
}

extern "C" void kernel_launch(void* const* d_in, const int* in_sizes, int n_in,
                              void* d_out, int out_size, void* d_ws, size_t ws_size,
                              hipStream_t stream) {
    const float4* pred = (const float4*)d_in[0];
    const float* tgt = (const float*)d_in[1];
    char* ws = (char*)d_ws;
    float* cost  = (float*)ws;                           // 2 MB
    u64* toplist = (u64*)(ws + (size_t)NT * NP * 4);     // 16 KB

    cost_kernel<<<dim3(NP / PB, NT / TT), 512, 0, stream>>>(pred, tgt, cost);
    topk_kernel<<<NT, 256, 0, stream>>>(cost, toplist);
    greedy_kernel<<<1, 64, 0, stream>>>(toplist, cost, (float*)d_out);
}